// Round 18
// baseline (367.136 us; speedup 1.0000x reference)
//
#include <hip/hip_runtime.h>
#include <hip/hip_bf16.h>

typedef __attribute__((ext_vector_type(8))) short short8;
typedef __attribute__((ext_vector_type(4))) float f32x4;
typedef __attribute__((ext_vector_type(4))) unsigned int u32x4;

__device__ __forceinline__ unsigned short f2b(float x){
  __hip_bfloat16 h = __float2bfloat16(x);
  union { __hip_bfloat16 h; unsigned short u; } cv;
  cv.h = h; return cv.u;
}

// ---------------- workspace layout (bytes) ----------------
#define OFF_SBA    0
#define OFF_SBD    1024
#define OFF_SPA16  2048          // spa embed bf16 [32][64] packed (4KB)
#define OFF_W2AB   8704          // je_w2 bf16 [64][64] (8KB)
#define OFF_W2DB   16896         // df_w2 bf16 [64][64] (8KB)
#define OFF_BN2SB  25088         // BN2 scale/bias (2KB)
#define OFF_ATB    27648         // A^T = W2^T W1 bf16 [128][128] (32KB)
#define OFF_VVB    60416         // VV bf16 [16][128] (4KB) row0=vv
#define OFF_WGB    64512         // gw bf16 [256][128] (64KB)
#define OFF_WG1B   130048        // gw1 bf16 [256][128] (64KB)
#define OFF_PART   195584        // partials [2048][512] f32 (4MB)
#define OFF_EXT    4389888       // ext f32 [16384][256] (16.8MB)
#define OFF_XBUF   21167104     // X bf16 [16384][32][128] pre-swizzled (134MB)

// ---------------- kpre: merged preps ----------------
// bid 0..127: weight casts; 128: vv+VVb; 129..192: AT; 193: spa; 194..343: BN1
__global__ __launch_bounds__(256) void kpre(
    const float* __restrict__ gw,  const float* __restrict__ gw1,
    const float* __restrict__ je_w2, const float* __restrict__ df_w2,
    const float* __restrict__ g1_w, const float* __restrict__ g2_w,
    const float* __restrict__ g1_b,
    const float* __restrict__ sp_w1, const float* __restrict__ sp_b1,
    const float* __restrict__ sp_w2, const float* __restrict__ sp_b2,
    const float* __restrict__ spa,
    const float* __restrict__ Angle, const float* __restrict__ dif,
    const float* __restrict__ je_g, const float* __restrict__ je_b,
    const float* __restrict__ df_g, const float* __restrict__ df_b,
    __hip_bfloat16* WG, __hip_bfloat16* WG1,
    __hip_bfloat16* W2ab, __hip_bfloat16* W2db,
    __hip_bfloat16* ATb, __hip_bfloat16* VVb,
    unsigned short* spa16, float* sbA, float* sbD)
{
  __shared__ char buf[32768];
  const int bid = blockIdx.x, tid = threadIdx.x;

  if (bid < 128){
    int base = bid*256 + tid, stride = 128*256;
    for (int i = base; i < 32768; i += stride){
      WG[i]  = __float2bfloat16(gw[i]);
      WG1[i] = __float2bfloat16(gw1[i]);
    }
    for (int i = base; i < 4096; i += stride){
      W2ab[i] = __float2bfloat16(je_w2[i]);
      W2db[i] = __float2bfloat16(df_w2[i]);
    }
  } else if (bid == 128){
    float* vv = (float*)buf;
    if (tid < 128){
      float acc = 0.f;
      for (int o = 0; o < 256; ++o) acc += g2_w[o*128 + tid] * g1_b[o];
      vv[tid] = acc;
    }
    __syncthreads();
    for (int i = tid; i < 2048; i += 256)
      VVb[i] = __float2bfloat16((i >> 7) == 0 ? vv[i & 127] : 0.f);
  } else if (bid < 193){
    float (*s1)[16] = (float(*)[16])buf;
    float (*s2)[16] = (float(*)[16])(buf + 4096);
    int bb = bid - 129;
    int bx = bb & 7, by = bb >> 3;
    int tc = tid & 15, tr = tid >> 4;
    float acc = 0.f;
    for (int och = 0; och < 4; ++och){
      for (int k = 0; k < 4; ++k){
        int idx = k*256 + tid;
        int ol = idx >> 4, cc = idx & 15;
        s1[ol][cc] = g1_w[(och*64 + ol)*128 + bx*16 + cc];
        s2[ol][cc] = g2_w[(och*64 + ol)*128 + by*16 + cc];
      }
      __syncthreads();
      for (int ol = 0; ol < 64; ++ol) acc += s2[ol][tr] * s1[ol][tc];
      __syncthreads();
    }
    ATb[(by*16 + tr)*128 + bx*16 + tc] = __float2bfloat16(acc);
  } else if (bid == 193){
    float* w1s = (float*)buf;            // 1600 f
    float* sps = (float*)(buf + 6400);   // 625 f
    float* w2s = (float*)(buf + 8960);   // 4096 f
    float (*r)[26] = (float(*)[26])(buf + 25344);
    for (int i = tid; i < 1600; i += 256) w1s[i] = sp_w1[i];
    for (int i = tid; i < 625;  i += 256) sps[i] = spa[i];
    for (int i = tid; i < 4096; i += 256) w2s[i] = sp_w2[i];
    __syncthreads();
    for (int i = tid; i < 1600; i += 256){
      int o = i/25, j = i%25;
      float acc = sp_b1[o];
      for (int c = 0; c < 25; ++c) acc += w1s[o*25 + c] * sps[c*25 + j];
      r[o][j] = fmaxf(acc, 0.f);
    }
    __syncthreads();
    for (int i = tid; i < 2048; i += 256){
      int j = i >> 6, o2 = i & 63;
      float acc = 0.f;
      if (j < 25){
        acc = sp_b2[o2];
        for (int c = 0; c < 64; ++c) acc += w2s[o2*64 + c] * r[c][j];
        acc = fmaxf(acc, 0.f);
      }
      spa16[j*64 + o2] = f2b(acc);
    }
  } else {
    float* red  = (float*)buf;
    float* red2 = (float*)(buf + 1024);
    int blk = bid - 194;
    int which = blk / 75, cj = blk % 75;
    const float* x = which ? dif : Angle;
    float s = 0.f, q = 0.f;
    for (int i = tid; i < 16384; i += 256){
      int b = i >> 9, t = i & 511;
      float v = x[((size_t)b*75 + cj)*512 + t];
      s += v; q += v*v;
    }
    red[tid] = s; red2[tid] = q;
    __syncthreads();
    for (int off = 128; off > 0; off >>= 1){
      if (tid < off){ red[tid] += red[tid+off]; red2[tid] += red2[tid+off]; }
      __syncthreads();
    }
    if (tid == 0){
      float m = red[0] * (1.f/16384.f);
      float v = red2[0] * (1.f/16384.f) - m*m;
      float rstd = rsqrtf(v + 1e-5f);
      float g = (which ? df_g : je_g)[cj];
      float be = (which ? df_b : je_b)[cj];
      float sc = g * rstd;
      float* dst = which ? sbD : sbA;
      dst[cj*2]   = sc;
      dst[cj*2+1] = be - m*sc;
    }
  }
}

__device__ __forceinline__ short8 ldfrag(const char* p){
  return *reinterpret_cast<const short8*>(p);
}
__device__ __forceinline__ short8 gfrag(const unsigned short* p){
  return *reinterpret_cast<const short8*>(p);
}

// ---------------- kembed2: conv1 VALU (LDS weights) + conv2 MFMA ----------------
__global__ __launch_bounds__(256, 2) void kembed2(
    const float* __restrict__ Angle, const float* __restrict__ dif,
    const float* __restrict__ sbA, const float* __restrict__ sbD,
    const float* __restrict__ w1a, const float* __restrict__ b1a,
    const unsigned short* __restrict__ W2ab, const float* __restrict__ b2a,
    const float* __restrict__ w1d, const float* __restrict__ b1d,
    const unsigned short* __restrict__ W2db, const float* __restrict__ b2d,
    const unsigned short* __restrict__ spa16, unsigned short* __restrict__ X)
{
  __shared__ char lds[65536];
  char* hb = lds;
  char* ob = lds + 32768;
  const int tid = threadIdx.x;
  const int lane = tid & 63;
  const int w = tid >> 6;
  const int l15 = lane & 15;
  const int g = lane >> 4;
  const int tok0 = blockIdx.x * 4;
  const int b = tok0 >> 9;

  // ---- phase0: stage packed conv1 weights into ob rows 0..15 bytes 0..127 ----
  for (int idx = tid; idx < 512; idx += 256){
    int c = idx >> 3, e = idx & 7;
    float v;
    if (e < 3)       v = w1a[c*3 + e];
    else if (e == 3) v = b1a[c];
    else if (e < 7)  v = w1d[c*3 + (e - 4)];
    else             v = b1d[c];
    int bo = c*32 + ((e >= 4) ? 16 : 0) + (e & 3)*4;
    *(float*)(ob + (bo >> 7)*256 + (bo & 127)) = v;
  }
  __syncthreads();

  // ---- phase1 ----
  {
    int j = tid >> 3, sub = tid & 7, tl = sub >> 1, half = sub & 1;
    int row = tl*32 + j;
    int rsw = (row & 7) << 4;
    int t = (tok0 & 511) + tl;
    bool act = (j < 25);
    float xa[3], xd[3];
    if (act){
      #pragma unroll
      for (int cc = 0; cc < 3; ++cc){
        int cj = cc*25 + j;
        size_t off = ((size_t)(b*3+cc)*25 + j)*512 + t;
        xa[cc] = Angle[off]*sbA[2*cj] + sbA[2*cj+1];
        xd[cc] = dif[off]*sbD[2*cj] + sbD[2*cj+1];
      }
    }
    #pragma unroll
    for (int cblk = 0; cblk < 4; ++cblk){
      int base = half*32 + cblk*8;
      union { unsigned short us[8]; uint4 v; } pa, pd;
      #pragma unroll
      for (int k = 0; k < 8; ++k){
        int c = base + k;
        int bo = c*32;
        float4 fa = *(const float4*)(ob + (bo >> 7)*256 + (bo & 127));
        float4 fd = *(const float4*)(ob + ((bo+16) >> 7)*256 + ((bo+16) & 127));
        float ha = 0.f, hd = 0.f;
        if (act){
          ha = fmaxf(fa.w + fa.x*xa[0] + fa.y*xa[1] + fa.z*xa[2], 0.f);
          hd = fmaxf(fd.w + fd.x*xd[0] + fd.y*xd[1] + fd.z*xd[2], 0.f);
        }
        pa.us[k] = f2b(ha);
        pd.us[k] = f2b(hd);
      }
      *reinterpret_cast<uint4*>(hb + row*256 + ((2*base) ^ rsw)) = pa.v;
      *reinterpret_cast<uint4*>(hb + row*256 + ((128 + 2*base) ^ rsw)) = pd.v;
      uint4 ps = *(const uint4*)(spa16 + j*64 + base);
      *reinterpret_cast<uint4*>(ob + row*256 + ((128 + 2*base) ^ rsw)) = ps;
    }
  }
  __syncthreads();

  // ---- phase2 ----
  {
    short8 w2fa[4][2], w2fd[4][2];
    float ba4[4], bd4[4];
    #pragma unroll
    for (int nt = 0; nt < 4; ++nt){
      #pragma unroll
      for (int kk = 0; kk < 2; ++kk){
        w2fa[nt][kk] = gfrag(W2ab + (nt*16 + l15)*64 + kk*32 + g*8);
        w2fd[nt][kk] = gfrag(W2db + (nt*16 + l15)*64 + kk*32 + g*8);
      }
      ba4[nt] = b2a[nt*16 + l15];
      bd4[nt] = b2d[nt*16 + l15];
    }
    #pragma unroll
    for (int mt = 0; mt < 2; ++mt){
      int arow = w*32 + mt*16 + l15;
      f32x4 aA[4], aD[4];
      #pragma unroll
      for (int nt = 0; nt < 4; ++nt){
        f32x4 va = {ba4[nt], ba4[nt], ba4[nt], ba4[nt]};
        f32x4 vd = {bd4[nt], bd4[nt], bd4[nt], bd4[nt]};
        aA[nt] = va; aD[nt] = vd;
      }
      #pragma unroll
      for (int kk = 0; kk < 2; ++kk){
        int cba = (kk*64 + g*16) ^ ((l15 & 7) << 4);
        int cbd = ((128 + kk*64 + g*16)) ^ ((l15 & 7) << 4);
        short8 hA = ldfrag(hb + arow*256 + cba);
        short8 hD = ldfrag(hb + arow*256 + cbd);
        #pragma unroll
        for (int nt = 0; nt < 4; ++nt){
          aA[nt] = __builtin_amdgcn_mfma_f32_16x16x32_bf16(hA, w2fa[nt][kk], aA[nt], 0, 0, 0);
          aD[nt] = __builtin_amdgcn_mfma_f32_16x16x32_bf16(hD, w2fd[nt][kk], aD[nt], 0, 0, 0);
        }
      }
      #pragma unroll
      for (int nt = 0; nt < 4; ++nt)
        #pragma unroll
        for (int r = 0; r < 4; ++r){
          int row2 = w*32 + mt*16 + g*4 + r;
          float v = fmaxf(aA[nt][r], 0.f) + fmaxf(aD[nt][r], 0.f);
          if ((row2 & 31) >= 25) v = 0.f;
          int chb = (nt*16 + l15)*2;
          int addr = row2*256 + ((chb & ~15) ^ ((row2 & 7) << 4)) + (chb & 15);
          *(unsigned short*)(ob + addr) = f2b(v);
        }
    }
  }
  __syncthreads();

  // ---- copyout ----
  {
    const uint4* ot = (const uint4*)ob;
    uint4* Xg = (uint4*)X;
    #pragma unroll
    for (int i2 = 0; i2 < 8; ++i2){
      int idx = i2*256 + tid;
      int trow = idx >> 4, off = idx & 15;
      Xg[((size_t)(tok0 + (trow >> 5)))*512 + (size_t)(trow & 31)*16 + off] = ot[idx];
    }
  }
}

// ---------------- kfuse: all weights inline, live set ~70 VGPR, 3 blocks/CU ----------------
#define FXS   0        // X [32][128] bf16 swz (8KB) — read only at loop top (xc regs)
#define FY    8192     // Y [32][128] bf16 swz (8KB)
#define FZT   16384    // ZT [256][40] bf16 (20KB) — wave-private slices
#define FGT   36864    // GT [32][40] bf16 (2.5KB)
#define FWS   39424    // WS f32[32]
#define FLDS  39552

__global__ __launch_bounds__(512, 3) void kfuse(
    const unsigned short* __restrict__ X,     // bf16 [16384][32][128] pre-swizzled
    const unsigned short* __restrict__ ATb,
    const unsigned short* __restrict__ VVb,
    const unsigned short* __restrict__ WGb,
    const unsigned short* __restrict__ WG1b,
    const float* __restrict__ g_gw1b, const float* __restrict__ gbn_g,
    float* __restrict__ ext, float* __restrict__ partials)
{
  __shared__ char lds[FLDS];
  const int tid  = threadIdx.x;
  const int lane = tid & 63;
  const int w    = tid >> 6;      // wave 0..7
  const int l15  = lane & 15;
  const int g    = lane >> 4;
  const int swz  = (l15 & 7) << 4;

  float bh[2]; bool sg[2]; int oc_[2];
  #pragma unroll
  for (int n = 0; n < 2; ++n){
    int oc = w*32 + n*16 + l15;
    oc_[n] = oc;
    bh[n] = g_gw1b[oc];
    sg[n] = (gbn_g[oc] >= 0.f);
  }
  float rs[2] = {0.f,0.f}, rq[2] = {0.f,0.f};

  {
    const u32x4* tok = reinterpret_cast<const u32x4*>(X + (size_t)(blockIdx.x*8)*4096);
    u32x4 p = tok[tid];
    *reinterpret_cast<u32x4*>(lds + FXS + tid*16) = p;
  }
  __syncthreads();

  for (int it = 0; it < 8; ++it){
    const int token = blockIdx.x*8 + it;

    int ntok = (it < 7) ? token + 1 : token;
    const u32x4* np = reinterpret_cast<const u32x4*>(X + (size_t)ntok*4096);
    u32x4 pfx = np[tid];     // in flight through P1 (covers L2/L3 latency)

    // ---- X fragments once into registers (32 VGPR); LDS X dead after this ----
    short8 xc[4][2];
    #pragma unroll
    for (int kk = 0; kk < 4; ++kk){
      int cb = (kk*64 + g*16) ^ swz;
      xc[kk][0] = ldfrag(lds + FXS + l15*256 + cb);
      xc[kk][1] = ldfrag(lds + FXS + (16 + l15)*256 + cb);
    }

    // ======== P1a: Y slice = X * AT (inline AT frags) ; w0: vv -> WS ========
    {
      f32x4 ay0 = {0.f,0.f,0.f,0.f}, ay1 = {0.f,0.f,0.f,0.f};
      #pragma unroll
      for (int kk = 0; kk < 4; ++kk){
        short8 atf = gfrag(ATb + (w*16 + l15)*128 + kk*32 + g*8);
        ay0 = __builtin_amdgcn_mfma_f32_16x16x32_bf16(xc[kk][0], atf, ay0, 0, 0, 0);
        ay1 = __builtin_amdgcn_mfma_f32_16x16x32_bf16(xc[kk][1], atf, ay1, 0, 0, 0);
      }
      int col2 = (w*16 + l15)*2;
      #pragma unroll
      for (int r = 0; r < 4; ++r){
        int row0 = g*4 + r, row1 = 16 + g*4 + r;
        *(unsigned short*)(lds + FY + row0*256 + (col2 ^ ((row0&7)<<4))) = f2b(ay0[r]);
        *(unsigned short*)(lds + FY + row1*256 + (col2 ^ ((row1&7)<<4))) = f2b(ay1[r]);
      }
      if (w == 0){
        f32x4 aw0 = {0.f,0.f,0.f,0.f}, aw1 = {0.f,0.f,0.f,0.f};
        #pragma unroll
        for (int kk = 0; kk < 4; ++kk){
          short8 vfr = gfrag(VVb + l15*128 + kk*32 + g*8);
          aw0 = __builtin_amdgcn_mfma_f32_16x16x32_bf16(xc[kk][0], vfr, aw0, 0, 0, 0);
          aw1 = __builtin_amdgcn_mfma_f32_16x16x32_bf16(xc[kk][1], vfr, aw1, 0, 0, 0);
        }
        if (l15 == 0){
          #pragma unroll
          for (int r = 0; r < 4; ++r){
            *(float*)(lds + FWS + (g*4 + r)*4) = aw0[r];
            *(float*)(lds + FWS + (16 + g*4 + r)*4) = aw1[r];
          }
        }
      }
    }

    // ======== P1b: Z slice = X * gw^T (wave-private ZT rows) ========
    #pragma unroll
    for (int nt = 0; nt < 2; ++nt){
      int ocn = w*32 + nt*16 + l15;
      f32x4 az0 = {0.f,0.f,0.f,0.f}, az1 = {0.f,0.f,0.f,0.f};
      #pragma unroll
      for (int kk = 0; kk < 4; ++kk){
        short8 bz = gfrag(WGb + (size_t)ocn*128 + kk*32 + g*8);
        az0 = __builtin_amdgcn_mfma_f32_16x16x32_bf16(xc[kk][0], bz, az0, 0, 0, 0);
        az1 = __builtin_amdgcn_mfma_f32_16x16x32_bf16(xc[kk][1], bz, az1, 0, 0, 0);
      }
      union { unsigned short us[4]; uint2 v; } pk0, pk1;
      #pragma unroll
      for (int r = 0; r < 4; ++r){ pk0.us[r] = f2b(az0[r]); pk1.us[r] = f2b(az1[r]); }
      *(uint2*)(lds + FZT + ocn*80 + (g*4)*2)      = pk0.v;
      *(uint2*)(lds + FZT + ocn*80 + (16 + g*4)*2) = pk1.v;
    }
    __syncthreads();                               // barA: Y, ZT, WS ready; all xc loads done

    // stage next token into XS (safe: every wave's xc loads precede barA;
    // store published to next iteration's xc loads by barB)
    *reinterpret_cast<u32x4*>(lds + FXS + tid*16) = pfx;

    f32x4 ah[2][2];
    #pragma unroll
    for (int nt = 0; nt < 2; ++nt){
      f32x4 b4 = {bh[nt], bh[nt], bh[nt], bh[nt]};
      ah[0][nt] = b4; ah[1][nt] = b4;
    }

    // ======== P2 window: waves 0,1: S^T = X * Y^T, lane-local softmax ========
    if (w < 2){
      __builtin_amdgcn_s_setprio(1);
      f32x4 asT0 = {0.f,0.f,0.f,0.f}, asT1 = {0.f,0.f,0.f,0.f};
      #pragma unroll
      for (int kk = 0; kk < 4; ++kk){
        int cb = (kk*64 + g*16) ^ swz;
        short8 ya = ldfrag(lds + FY + (w*16 + l15)*256 + cb);
        asT0 = __builtin_amdgcn_mfma_f32_16x16x32_bf16(xc[kk][0], ya, asT0, 0, 0, 0);
        asT1 = __builtin_amdgcn_mfma_f32_16x16x32_bf16(xc[kk][1], ya, asT1, 0, 0, 0);
      }
      float4 wlo = *(const float4*)(lds + FWS + g*16);
      float4 whi = *(const float4*)(lds + FWS + 64 + g*16);
      float v0[4], v1[4];
      v0[0] = asT0[0] + wlo.x; v0[1] = asT0[1] + wlo.y;
      v0[2] = asT0[2] + wlo.z; v0[3] = asT0[3] + wlo.w;
      v1[0] = asT1[0] + whi.x; v1[1] = asT1[1] + whi.y;
      v1[2] = asT1[2] + whi.z; v1[3] = asT1[3] + whi.w;
      #pragma unroll
      for (int r = 0; r < 4; ++r)
        if (g*4 + r >= 9) v1[r] = -3.0e38f;
      float m = fmaxf(fmaxf(fmaxf(v0[0], v0[1]), fmaxf(v0[2], v0[3])),
                      fmaxf(fmaxf(v1[0], v1[1]), fmaxf(v1[2], v1[3])));
      m = fmaxf(m, __shfl_xor(m, 16));
      m = fmaxf(m, __shfl_xor(m, 32));
      float e0[4], e1[4]; float s = 0.f;
      #pragma unroll
      for (int r = 0; r < 4; ++r){
        e0[r] = __expf(v0[r] - m);
        e1[r] = (g*4 + r < 9) ? __expf(v1[r] - m) : 0.f;
        s += e0[r] + e1[r];
      }
      s += __shfl_xor(s, 16);
      s += __shfl_xor(s, 32);
      float inv = 1.f / s;
      union { unsigned short us[4]; uint2 v; } gp0, gp1;
      #pragma unroll
      for (int r = 0; r < 4; ++r){ gp0.us[r] = f2b(e0[r]*inv); gp1.us[r] = f2b(e1[r]*inv); }
      char* grow = lds + FGT + (w*16 + l15)*80;
      *(uint2*)(grow + g*8)      = gp0.v;
      *(uint2*)(grow + 32 + g*8) = gp1.v;
      __builtin_amdgcn_s_setprio(0);
      #pragma unroll
      for (int kk = 0; kk < 4; ++kk)
        #pragma unroll
        for (int nt = 0; nt < 2; ++nt){
          short8 b1f = gfrag(WG1b + (size_t)(w*32 + nt*16 + l15)*128 + kk*32 + g*8);
          ah[0][nt] = __builtin_amdgcn_mfma_f32_16x16x32_bf16(xc[kk][0], b1f, ah[0][nt], 0, 0, 0);
          ah[1][nt] = __builtin_amdgcn_mfma_f32_16x16x32_bf16(xc[kk][1], b1f, ah[1][nt], 0, 0, 0);
        }
    } else {
      #pragma unroll
      for (int kk = 0; kk < 4; ++kk)
        #pragma unroll
        for (int nt = 0; nt < 2; ++nt){
          short8 b1f = gfrag(WG1b + (size_t)(w*32 + nt*16 + l15)*128 + kk*32 + g*8);
          ah[0][nt] = __builtin_amdgcn_mfma_f32_16x16x32_bf16(xc[kk][0], b1f, ah[0][nt], 0, 0, 0);
          ah[1][nt] = __builtin_amdgcn_mfma_f32_16x16x32_bf16(xc[kk][1], b1f, ah[1][nt], 0, 0, 0);
        }
    }
    __syncthreads();                               // barB: GT + XS(next) published

    // ======== P3: ah += G * Z ========
    {
      short8 ga0 = ldfrag(lds + FGT + l15*80 + g*16);
      short8 ga1 = ldfrag(lds + FGT + (16 + l15)*80 + g*16);
      #pragma unroll
      for (int nt = 0; nt < 2; ++nt){
        short8 zb = ldfrag(lds + FZT + (w*32 + nt*16 + l15)*80 + g*16);
        ah[0][nt] = __builtin_amdgcn_mfma_f32_16x16x32_bf16(ga0, zb, ah[0][nt], 0, 0, 0);
        ah[1][nt] = __builtin_amdgcn_mfma_f32_16x16x32_bf16(ga1, zb, ah[1][nt], 0, 0, 0);
      }
    }

    // ---- epilogue: BN2 partials (rows<25) + per-token extreme ----
    #pragma unroll
    for (int n = 0; n < 2; ++n){
      float e = sg[n] ? -3.0e38f : 3.0e38f;
      #pragma unroll
      for (int mt = 0; mt < 2; ++mt)
        #pragma unroll
        for (int r = 0; r < 4; ++r){
          int row = mt*16 + g*4 + r;
          if (row < 25){
            float v = ah[mt][n][r];
            rs[n] += v; rq[n] += v*v;
            e = sg[n] ? fmaxf(e, v) : fminf(e, v);
          }
        }
      float e2 = __shfl_xor(e, 16);
      e = sg[n] ? fmaxf(e, e2) : fminf(e, e2);
      e2 = __shfl_xor(e, 32);
      e = sg[n] ? fmaxf(e, e2) : fminf(e, e2);
      if (g == 0) ext[(size_t)token*256 + oc_[n]] = e;
    }
  }

  // ---- block partials for BN2 ----
  #pragma unroll
  for (int n = 0; n < 2; ++n){
    float s = rs[n], q = rq[n];
    s += __shfl_xor(s, 16); s += __shfl_xor(s, 32);
    q += __shfl_xor(q, 16); q += __shfl_xor(q, 32);
    if (g == 0){
      partials[(size_t)blockIdx.x*512 + oc_[n]]       = s;
      partials[(size_t)blockIdx.x*512 + 256 + oc_[n]] = q;
    }
  }
}

// ---------------- BN2 finalize ----------------
__global__ void kbn2(const float* __restrict__ partials,
                     const float* __restrict__ gg, const float* __restrict__ gb,
                     float* sb)
{
  __shared__ float red[256];
  __shared__ float red2[256];
  int oc = blockIdx.x, tid = threadIdx.x;
  float s = 0.f, q = 0.f;
  for (int i = tid; i < 2048; i += 256){
    s += partials[(size_t)i*512 + oc];
    q += partials[(size_t)i*512 + 256 + oc];
  }
  red[tid] = s; red2[tid] = q;
  __syncthreads();
  for (int off = 128; off > 0; off >>= 1){
    if (tid < off){ red[tid] += red[tid+off]; red2[tid] += red2[tid+off]; }
    __syncthreads();
  }
  if (tid == 0){
    float m = red[0] * (1.f/409600.f);
    float v = red2[0] * (1.f/409600.f) - m*m;
    float rstd = rsqrtf(v + 1e-5f);
    float sc = gg[oc]*rstd;
    sb[oc*2]   = sc;
    sb[oc*2+1] = gb[oc] - m*sc;
  }
}

// ---------------- pass2 ----------------
__global__ void kpass2(const float* __restrict__ ext, const float* __restrict__ sb,
                       float* __restrict__ out)
{
  __shared__ float st[32][257];
  int b = blockIdx.x >> 4, tc = blockIdx.x & 15;
  int t0 = tc*32, tid = threadIdx.x;
  for (int i = tid; i < 32*256; i += 256){
    int tt = i >> 8, oc = i & 255;
    float v = ext[((size_t)(b*512) + t0 + tt)*256 + oc];
    st[tt][oc] = fmaxf(v*sb[oc*2] + sb[oc*2+1], 0.f);
  }
  __syncthreads();
  for (int i = tid; i < 32*256; i += 256){
    int oc = i >> 5, tt = i & 31;
    out[((size_t)(b*256) + oc)*512 + t0 + tt] = st[tt][oc];
  }
}

extern "C" void kernel_launch(void* const* d_in, const int* in_sizes, int n_in,
                              void* d_out, int out_size, void* d_ws, size_t ws_size,
                              hipStream_t stream)
{
  (void)in_sizes; (void)n_in; (void)out_size; (void)ws_size;
  const float* Angle = (const float*)d_in[0];
  const float* dif   = (const float*)d_in[1];
  const float* spa   = (const float*)d_in[2];
  const float* je_g  = (const float*)d_in[3];
  const float* je_b  = (const float*)d_in[4];
  const float* je_w1 = (const float*)d_in[5];
  const float* je_b1 = (const float*)d_in[6];
  const float* je_w2 = (const float*)d_in[7];
  const float* je_b2 = (const float*)d_in[8];
  const float* df_g  = (const float*)d_in[9];
  const float* df_b  = (const float*)d_in[10];
  const float* df_w1 = (const float*)d_in[11];
  const float* df_b1 = (const float*)d_in[12];
  const float* df_w2 = (const float*)d_in[13];
  const float* df_b2 = (const float*)d_in[14];
  const float* sp_w1 = (const float*)d_in[15];
  const float* sp_b1 = (const float*)d_in[16];
  const float* sp_w2 = (const float*)d_in[17];
  const float* sp_b2 = (const float*)d_in[18];
  const float* g1_w  = (const float*)d_in[19];
  const float* g1_b  = (const float*)d_in[20];
  const float* g2_w  = (const float*)d_in[21];
  const float* g2_b  = (const float*)d_in[22];
  const float* gw    = (const float*)d_in[23];
  const float* gw1   = (const float*)d_in[24];
  const float* gw1_b = (const float*)d_in[25];
  const float* gbn_g = (const float*)d_in[26];
  const float* gbn_b = (const float*)d_in[27];
  (void)g2_b;

  char* ws = (char*)d_ws;
  float* sbA     = (float*)(ws + OFF_SBA);
  float* sbD     = (float*)(ws + OFF_SBD);
  unsigned short* spa16 = (unsigned short*)(ws + OFF_SPA16);
  __hip_bfloat16* W2ab = (__hip_bfloat16*)(ws + OFF_W2AB);
  __hip_bfloat16* W2db = (__hip_bfloat16*)(ws + OFF_W2DB);
  float* bn2sb   = (float*)(ws + OFF_BN2SB);
  __hip_bfloat16* ATb  = (__hip_bfloat16*)(ws + OFF_ATB);
  __hip_bfloat16* VVb  = (__hip_bfloat16*)(ws + OFF_VVB);
  __hip_bfloat16* WGb  = (__hip_bfloat16*)(ws + OFF_WGB);
  __hip_bfloat16* WG1b = (__hip_bfloat16*)(ws + OFF_WG1B);
  float* partials = (float*)(ws + OFF_PART);
  float* ext      = (float*)(ws + OFF_EXT);
  unsigned short* X = (unsigned short*)(ws + OFF_XBUF);

  kpre<<<344, 256, 0, stream>>>(gw, gw1, je_w2, df_w2, g1_w, g2_w, g1_b,
                                sp_w1, sp_b1, sp_w2, sp_b2, spa,
                                Angle, dif, je_g, je_b, df_g, df_b,
                                WGb, WG1b, W2ab, W2db, ATb, VVb,
                                spa16, sbA, sbD);
  kembed2<<<4096, 256, 0, stream>>>(Angle, dif, sbA, sbD,
                                    je_w1, je_b1, (const unsigned short*)W2ab, je_b2,
                                    df_w1, df_b1, (const unsigned short*)W2db, df_b2,
                                    spa16, X);
  kfuse<<<2048, 512, 0, stream>>>(X,
                                  (const unsigned short*)ATb,
                                  (const unsigned short*)VVb,
                                  (const unsigned short*)WGb,
                                  (const unsigned short*)WG1b,
                                  gw1_b, gbn_g, ext, partials);
  kbn2<<<256, 256, 0, stream>>>(partials, gbn_g, gbn_b, bn2sb);
  kpass2<<<512, 256, 0, stream>>>(ext, bn2sb, (float*)d_out);
}

// Round 19
// 306.406 us; speedup vs baseline: 1.1982x; 1.1982x over previous
//
#include <hip/hip_runtime.h>
#include <hip/hip_bf16.h>

typedef __attribute__((ext_vector_type(8))) short short8;
typedef __attribute__((ext_vector_type(4))) float f32x4;
typedef __attribute__((ext_vector_type(4))) unsigned int u32x4;

__device__ __forceinline__ unsigned short f2b(float x){
  __hip_bfloat16 h = __float2bfloat16(x);
  union { __hip_bfloat16 h; unsigned short u; } cv;
  cv.h = h; return cv.u;
}

// ---------------- workspace layout (bytes) ----------------
#define OFF_SBA    0
#define OFF_SBD    1024
#define OFF_SPA16  2048          // spa embed bf16 [32][64] packed (4KB)
#define OFF_W2AB   8704          // je_w2 bf16 [64][64] (8KB)
#define OFF_W2DB   16896         // df_w2 bf16 [64][64] (8KB)
#define OFF_BN2SB  25088         // BN2 scale/bias (2KB)
#define OFF_ATB    27648         // A^T = W2^T W1 bf16 [128][128] (32KB)
#define OFF_VVB    60416         // VV bf16 [16][128] (4KB) row0=vv
#define OFF_WGB    64512         // gw bf16 [256][128] (64KB)
#define OFF_WG1B   130048        // gw1 bf16 [256][128] (64KB)
#define OFF_PART   195584        // partials [2048][512] f32 (4MB)
#define OFF_EXT    4389888       // ext f32 [16384][256] (16.8MB)
#define OFF_XBUF   21167104      // X bf16 [16384][32][128] pre-swizzled (134MB)

// ---------------- kpre: merged preps ----------------
// bid 0..127: weight casts; 128: vv+VVb; 129..192: AT; 193: spa; 194..343: BN1
__global__ __launch_bounds__(256) void kpre(
    const float* __restrict__ gw,  const float* __restrict__ gw1,
    const float* __restrict__ je_w2, const float* __restrict__ df_w2,
    const float* __restrict__ g1_w, const float* __restrict__ g2_w,
    const float* __restrict__ g1_b,
    const float* __restrict__ sp_w1, const float* __restrict__ sp_b1,
    const float* __restrict__ sp_w2, const float* __restrict__ sp_b2,
    const float* __restrict__ spa,
    const float* __restrict__ Angle, const float* __restrict__ dif,
    const float* __restrict__ je_g, const float* __restrict__ je_b,
    const float* __restrict__ df_g, const float* __restrict__ df_b,
    __hip_bfloat16* WG, __hip_bfloat16* WG1,
    __hip_bfloat16* W2ab, __hip_bfloat16* W2db,
    __hip_bfloat16* ATb, __hip_bfloat16* VVb,
    unsigned short* spa16, float* sbA, float* sbD)
{
  __shared__ char buf[32768];
  const int bid = blockIdx.x, tid = threadIdx.x;

  if (bid < 128){
    int base = bid*256 + tid, stride = 128*256;
    for (int i = base; i < 32768; i += stride){
      WG[i]  = __float2bfloat16(gw[i]);
      WG1[i] = __float2bfloat16(gw1[i]);
    }
    for (int i = base; i < 4096; i += stride){
      W2ab[i] = __float2bfloat16(je_w2[i]);
      W2db[i] = __float2bfloat16(df_w2[i]);
    }
  } else if (bid == 128){
    float* vv = (float*)buf;
    if (tid < 128){
      float acc = 0.f;
      for (int o = 0; o < 256; ++o) acc += g2_w[o*128 + tid] * g1_b[o];
      vv[tid] = acc;
    }
    __syncthreads();
    for (int i = tid; i < 2048; i += 256)
      VVb[i] = __float2bfloat16((i >> 7) == 0 ? vv[i & 127] : 0.f);
  } else if (bid < 193){
    float (*s1)[16] = (float(*)[16])buf;
    float (*s2)[16] = (float(*)[16])(buf + 4096);
    int bb = bid - 129;
    int bx = bb & 7, by = bb >> 3;
    int tc = tid & 15, tr = tid >> 4;
    float acc = 0.f;
    for (int och = 0; och < 4; ++och){
      for (int k = 0; k < 4; ++k){
        int idx = k*256 + tid;
        int ol = idx >> 4, cc = idx & 15;
        s1[ol][cc] = g1_w[(och*64 + ol)*128 + bx*16 + cc];
        s2[ol][cc] = g2_w[(och*64 + ol)*128 + by*16 + cc];
      }
      __syncthreads();
      for (int ol = 0; ol < 64; ++ol) acc += s2[ol][tr] * s1[ol][tc];
      __syncthreads();
    }
    ATb[(by*16 + tr)*128 + bx*16 + tc] = __float2bfloat16(acc);
  } else if (bid == 193){
    float* w1s = (float*)buf;            // 1600 f
    float* sps = (float*)(buf + 6400);   // 625 f
    float* w2s = (float*)(buf + 8960);   // 4096 f
    float (*r)[26] = (float(*)[26])(buf + 25344);
    for (int i = tid; i < 1600; i += 256) w1s[i] = sp_w1[i];
    for (int i = tid; i < 625;  i += 256) sps[i] = spa[i];
    for (int i = tid; i < 4096; i += 256) w2s[i] = sp_w2[i];
    __syncthreads();
    for (int i = tid; i < 1600; i += 256){
      int o = i/25, j = i%25;
      float acc = sp_b1[o];
      for (int c = 0; c < 25; ++c) acc += w1s[o*25 + c] * sps[c*25 + j];
      r[o][j] = fmaxf(acc, 0.f);
    }
    __syncthreads();
    for (int i = tid; i < 2048; i += 256){
      int j = i >> 6, o2 = i & 63;
      float acc = 0.f;
      if (j < 25){
        acc = sp_b2[o2];
        for (int c = 0; c < 64; ++c) acc += w2s[o2*64 + c] * r[c][j];
        acc = fmaxf(acc, 0.f);
      }
      spa16[j*64 + o2] = f2b(acc);
    }
  } else {
    float* red  = (float*)buf;
    float* red2 = (float*)(buf + 1024);
    int blk = bid - 194;
    int which = blk / 75, cj = blk % 75;
    const float* x = which ? dif : Angle;
    float s = 0.f, q = 0.f;
    for (int i = tid; i < 16384; i += 256){
      int b = i >> 9, t = i & 511;
      float v = x[((size_t)b*75 + cj)*512 + t];
      s += v; q += v*v;
    }
    red[tid] = s; red2[tid] = q;
    __syncthreads();
    for (int off = 128; off > 0; off >>= 1){
      if (tid < off){ red[tid] += red[tid+off]; red2[tid] += red2[tid+off]; }
      __syncthreads();
    }
    if (tid == 0){
      float m = red[0] * (1.f/16384.f);
      float v = red2[0] * (1.f/16384.f) - m*m;
      float rstd = rsqrtf(v + 1e-5f);
      float g = (which ? df_g : je_g)[cj];
      float be = (which ? df_b : je_b)[cj];
      float sc = g * rstd;
      float* dst = which ? sbD : sbA;
      dst[cj*2]   = sc;
      dst[cj*2+1] = be - m*sc;
    }
  }
}

__device__ __forceinline__ short8 ldfrag(const char* p){
  return *reinterpret_cast<const short8*>(p);
}
__device__ __forceinline__ short8 gfrag(const unsigned short* p){
  return *reinterpret_cast<const short8*>(p);
}

// ---------------- kembed2: conv1 VALU (LDS weights) + conv2 MFMA ----------------
__global__ __launch_bounds__(256, 2) void kembed2(
    const float* __restrict__ Angle, const float* __restrict__ dif,
    const float* __restrict__ sbA, const float* __restrict__ sbD,
    const float* __restrict__ w1a, const float* __restrict__ b1a,
    const unsigned short* __restrict__ W2ab, const float* __restrict__ b2a,
    const float* __restrict__ w1d, const float* __restrict__ b1d,
    const unsigned short* __restrict__ W2db, const float* __restrict__ b2d,
    const unsigned short* __restrict__ spa16, unsigned short* __restrict__ X)
{
  __shared__ char lds[65536];
  char* hb = lds;
  char* ob = lds + 32768;
  const int tid = threadIdx.x;
  const int lane = tid & 63;
  const int w = tid >> 6;
  const int l15 = lane & 15;
  const int g = lane >> 4;
  const int tok0 = blockIdx.x * 4;
  const int b = tok0 >> 9;

  // ---- phase0: stage packed conv1 weights into ob rows 0..15 bytes 0..127 ----
  for (int idx = tid; idx < 512; idx += 256){
    int c = idx >> 3, e = idx & 7;
    float v;
    if (e < 3)       v = w1a[c*3 + e];
    else if (e == 3) v = b1a[c];
    else if (e < 7)  v = w1d[c*3 + (e - 4)];
    else             v = b1d[c];
    int bo = c*32 + ((e >= 4) ? 16 : 0) + (e & 3)*4;
    *(float*)(ob + (bo >> 7)*256 + (bo & 127)) = v;
  }
  __syncthreads();

  // ---- phase1 ----
  {
    int j = tid >> 3, sub = tid & 7, tl = sub >> 1, half = sub & 1;
    int row = tl*32 + j;
    int rsw = (row & 7) << 4;
    int t = (tok0 & 511) + tl;
    bool act = (j < 25);
    float xa[3], xd[3];
    if (act){
      #pragma unroll
      for (int cc = 0; cc < 3; ++cc){
        int cj = cc*25 + j;
        size_t off = ((size_t)(b*3+cc)*25 + j)*512 + t;
        xa[cc] = Angle[off]*sbA[2*cj] + sbA[2*cj+1];
        xd[cc] = dif[off]*sbD[2*cj] + sbD[2*cj+1];
      }
    }
    #pragma unroll
    for (int cblk = 0; cblk < 4; ++cblk){
      int base = half*32 + cblk*8;
      union { unsigned short us[8]; uint4 v; } pa, pd;
      #pragma unroll
      for (int k = 0; k < 8; ++k){
        int c = base + k;
        int bo = c*32;
        float4 fa = *(const float4*)(ob + (bo >> 7)*256 + (bo & 127));
        float4 fd = *(const float4*)(ob + ((bo+16) >> 7)*256 + ((bo+16) & 127));
        float ha = 0.f, hd = 0.f;
        if (act){
          ha = fmaxf(fa.w + fa.x*xa[0] + fa.y*xa[1] + fa.z*xa[2], 0.f);
          hd = fmaxf(fd.w + fd.x*xd[0] + fd.y*xd[1] + fd.z*xd[2], 0.f);
        }
        pa.us[k] = f2b(ha);
        pd.us[k] = f2b(hd);
      }
      *reinterpret_cast<uint4*>(hb + row*256 + ((2*base) ^ rsw)) = pa.v;
      *reinterpret_cast<uint4*>(hb + row*256 + ((128 + 2*base) ^ rsw)) = pd.v;
      uint4 ps = *(const uint4*)(spa16 + j*64 + base);
      *reinterpret_cast<uint4*>(ob + row*256 + ((128 + 2*base) ^ rsw)) = ps;
    }
  }
  __syncthreads();

  // ---- phase2 ----
  {
    short8 w2fa[4][2], w2fd[4][2];
    float ba4[4], bd4[4];
    #pragma unroll
    for (int nt = 0; nt < 4; ++nt){
      #pragma unroll
      for (int kk = 0; kk < 2; ++kk){
        w2fa[nt][kk] = gfrag(W2ab + (nt*16 + l15)*64 + kk*32 + g*8);
        w2fd[nt][kk] = gfrag(W2db + (nt*16 + l15)*64 + kk*32 + g*8);
      }
      ba4[nt] = b2a[nt*16 + l15];
      bd4[nt] = b2d[nt*16 + l15];
    }
    #pragma unroll
    for (int mt = 0; mt < 2; ++mt){
      int arow = w*32 + mt*16 + l15;
      f32x4 aA[4], aD[4];
      #pragma unroll
      for (int nt = 0; nt < 4; ++nt){
        f32x4 va = {ba4[nt], ba4[nt], ba4[nt], ba4[nt]};
        f32x4 vd = {bd4[nt], bd4[nt], bd4[nt], bd4[nt]};
        aA[nt] = va; aD[nt] = vd;
      }
      #pragma unroll
      for (int kk = 0; kk < 2; ++kk){
        int cba = (kk*64 + g*16) ^ ((l15 & 7) << 4);
        int cbd = ((128 + kk*64 + g*16)) ^ ((l15 & 7) << 4);
        short8 hA = ldfrag(hb + arow*256 + cba);
        short8 hD = ldfrag(hb + arow*256 + cbd);
        #pragma unroll
        for (int nt = 0; nt < 4; ++nt){
          aA[nt] = __builtin_amdgcn_mfma_f32_16x16x32_bf16(hA, w2fa[nt][kk], aA[nt], 0, 0, 0);
          aD[nt] = __builtin_amdgcn_mfma_f32_16x16x32_bf16(hD, w2fd[nt][kk], aD[nt], 0, 0, 0);
        }
      }
      #pragma unroll
      for (int nt = 0; nt < 4; ++nt)
        #pragma unroll
        for (int r = 0; r < 4; ++r){
          int row2 = w*32 + mt*16 + g*4 + r;
          float v = fmaxf(aA[nt][r], 0.f) + fmaxf(aD[nt][r], 0.f);
          if ((row2 & 31) >= 25) v = 0.f;
          int chb = (nt*16 + l15)*2;
          int addr = row2*256 + ((chb & ~15) ^ ((row2 & 7) << 4)) + (chb & 15);
          *(unsigned short*)(ob + addr) = f2b(v);
        }
    }
  }
  __syncthreads();

  // ---- copyout ----
  {
    const uint4* ot = (const uint4*)ob;
    uint4* Xg = (uint4*)X;
    #pragma unroll
    for (int i2 = 0; i2 < 8; ++i2){
      int idx = i2*256 + tid;
      int trow = idx >> 4, off = idx & 15;
      Xg[((size_t)(tok0 + (trow >> 5)))*512 + (size_t)(trow & 31)*16 + off] = ot[idx];
    }
  }
}

// ---------------- kfuse (R16 config): single X buffer, hoisted AT, g1f preload ----------------
#define FXS   0        // X [32][128] bf16 swz (8KB) — read only at loop top (xc regs)
#define FY    8192     // Y [32][128] bf16 swz (8KB)
#define FZT   16384    // ZT [256][40] bf16 (20KB) — wave-private slices
#define FGT   36864    // GT [32][40] bf16 (2.5KB)
#define FWS   39424    // WS f32[32]
#define FLDS  39552

__global__ __launch_bounds__(512, 2) void kfuse(
    const unsigned short* __restrict__ X,     // bf16 [16384][32][128] pre-swizzled
    const unsigned short* __restrict__ ATb,
    const unsigned short* __restrict__ VVb,
    const unsigned short* __restrict__ WGb,
    const unsigned short* __restrict__ WG1b,
    const float* __restrict__ g_gw1b, const float* __restrict__ gbn_g,
    float* __restrict__ ext, float* __restrict__ partials)
{
  __shared__ char lds[FLDS];
  const int tid  = threadIdx.x;
  const int lane = tid & 63;
  const int w    = tid >> 6;      // wave 0..7
  const int l15  = lane & 15;
  const int g    = lane >> 4;
  const int swz  = (l15 & 7) << 4;

  short8 atf[4];
  #pragma unroll
  for (int kk = 0; kk < 4; ++kk)
    atf[kk] = gfrag(ATb + (w*16 + l15)*128 + kk*32 + g*8);

  float bh[2]; bool sg[2]; int oc_[2];
  #pragma unroll
  for (int n = 0; n < 2; ++n){
    int oc = w*32 + n*16 + l15;
    oc_[n] = oc;
    bh[n] = g_gw1b[oc];
    sg[n] = (gbn_g[oc] >= 0.f);
  }
  float rs[2] = {0.f,0.f}, rq[2] = {0.f,0.f};

  {
    const u32x4* tok = reinterpret_cast<const u32x4*>(X + (size_t)(blockIdx.x*8)*4096);
    u32x4 p = tok[tid];
    *reinterpret_cast<u32x4*>(lds + FXS + tid*16) = p;
  }
  __syncthreads();

  for (int it = 0; it < 8; ++it){
    const int token = blockIdx.x*8 + it;

    int ntok = (it < 7) ? token + 1 : token;
    const u32x4* np = reinterpret_cast<const u32x4*>(X + (size_t)ntok*4096);
    u32x4 pfx = np[tid];     // in flight through P1 (covers L2/L3 latency)

    // ---- X fragments once into registers (32 VGPR); LDS X dead after this ----
    short8 xc[4][2];
    #pragma unroll
    for (int kk = 0; kk < 4; ++kk){
      int cb = (kk*64 + g*16) ^ swz;
      xc[kk][0] = ldfrag(lds + FXS + l15*256 + cb);
      xc[kk][1] = ldfrag(lds + FXS + (16 + l15)*256 + cb);
    }

    // ======== P1a: Y slice = X * AT ; w0: vv -> WS ========
    {
      f32x4 ay0 = {0.f,0.f,0.f,0.f}, ay1 = {0.f,0.f,0.f,0.f};
      #pragma unroll
      for (int kk = 0; kk < 4; ++kk){
        ay0 = __builtin_amdgcn_mfma_f32_16x16x32_bf16(xc[kk][0], atf[kk], ay0, 0, 0, 0);
        ay1 = __builtin_amdgcn_mfma_f32_16x16x32_bf16(xc[kk][1], atf[kk], ay1, 0, 0, 0);
      }
      int col2 = (w*16 + l15)*2;
      #pragma unroll
      for (int r = 0; r < 4; ++r){
        int row0 = g*4 + r, row1 = 16 + g*4 + r;
        *(unsigned short*)(lds + FY + row0*256 + (col2 ^ ((row0&7)<<4))) = f2b(ay0[r]);
        *(unsigned short*)(lds + FY + row1*256 + (col2 ^ ((row1&7)<<4))) = f2b(ay1[r]);
      }
      if (w == 0){
        f32x4 aw0 = {0.f,0.f,0.f,0.f}, aw1 = {0.f,0.f,0.f,0.f};
        #pragma unroll
        for (int kk = 0; kk < 4; ++kk){
          short8 vfr = gfrag(VVb + l15*128 + kk*32 + g*8);
          aw0 = __builtin_amdgcn_mfma_f32_16x16x32_bf16(xc[kk][0], vfr, aw0, 0, 0, 0);
          aw1 = __builtin_amdgcn_mfma_f32_16x16x32_bf16(xc[kk][1], vfr, aw1, 0, 0, 0);
        }
        if (l15 == 0){
          #pragma unroll
          for (int r = 0; r < 4; ++r){
            *(float*)(lds + FWS + (g*4 + r)*4) = aw0[r];
            *(float*)(lds + FWS + (16 + g*4 + r)*4) = aw1[r];
          }
        }
      }
    }

    // ======== P1b: Z slice = X * gw^T (wave-private ZT rows) ========
    #pragma unroll
    for (int nt = 0; nt < 2; ++nt){
      int ocn = w*32 + nt*16 + l15;
      f32x4 az0 = {0.f,0.f,0.f,0.f}, az1 = {0.f,0.f,0.f,0.f};
      #pragma unroll
      for (int kk = 0; kk < 4; ++kk){
        short8 bz = gfrag(WGb + (size_t)ocn*128 + kk*32 + g*8);
        az0 = __builtin_amdgcn_mfma_f32_16x16x32_bf16(xc[kk][0], bz, az0, 0, 0, 0);
        az1 = __builtin_amdgcn_mfma_f32_16x16x32_bf16(xc[kk][1], bz, az1, 0, 0, 0);
      }
      union { unsigned short us[4]; uint2 v; } pk0, pk1;
      #pragma unroll
      for (int r = 0; r < 4; ++r){ pk0.us[r] = f2b(az0[r]); pk1.us[r] = f2b(az1[r]); }
      *(uint2*)(lds + FZT + ocn*80 + (g*4)*2)      = pk0.v;
      *(uint2*)(lds + FZT + ocn*80 + (16 + g*4)*2) = pk1.v;
    }
    __syncthreads();                               // barA: Y, ZT, WS ready; all xc loads done

    // stage next token into XS (safe: every wave's xc loads precede barA;
    // store published to next iteration's xc loads by barB)
    *reinterpret_cast<u32x4*>(lds + FXS + tid*16) = pfx;

    // preload gw1 frags (consumed in the P2 window; latency hides under P2/S)
    short8 g1f[2][4];
    #pragma unroll
    for (int nt = 0; nt < 2; ++nt)
      #pragma unroll
      for (int kk = 0; kk < 4; ++kk)
        g1f[nt][kk] = gfrag(WG1b + (size_t)(w*32 + nt*16 + l15)*128 + kk*32 + g*8);

    f32x4 ah[2][2];
    #pragma unroll
    for (int nt = 0; nt < 2; ++nt){
      f32x4 b4 = {bh[nt], bh[nt], bh[nt], bh[nt]};
      ah[0][nt] = b4; ah[1][nt] = b4;
    }

    // ======== P2 window: waves 0,1: S^T = X * Y^T, lane-local softmax ========
    if (w < 2){
      __builtin_amdgcn_s_setprio(1);
      f32x4 asT0 = {0.f,0.f,0.f,0.f}, asT1 = {0.f,0.f,0.f,0.f};
      #pragma unroll
      for (int kk = 0; kk < 4; ++kk){
        int cb = (kk*64 + g*16) ^ swz;
        short8 ya = ldfrag(lds + FY + (w*16 + l15)*256 + cb);
        asT0 = __builtin_amdgcn_mfma_f32_16x16x32_bf16(xc[kk][0], ya, asT0, 0, 0, 0);
        asT1 = __builtin_amdgcn_mfma_f32_16x16x32_bf16(xc[kk][1], ya, asT1, 0, 0, 0);
      }
      float4 wlo = *(const float4*)(lds + FWS + g*16);
      float4 whi = *(const float4*)(lds + FWS + 64 + g*16);
      float v0[4], v1[4];
      v0[0] = asT0[0] + wlo.x; v0[1] = asT0[1] + wlo.y;
      v0[2] = asT0[2] + wlo.z; v0[3] = asT0[3] + wlo.w;
      v1[0] = asT1[0] + whi.x; v1[1] = asT1[1] + whi.y;
      v1[2] = asT1[2] + whi.z; v1[3] = asT1[3] + whi.w;
      #pragma unroll
      for (int r = 0; r < 4; ++r)
        if (g*4 + r >= 9) v1[r] = -3.0e38f;
      float m = fmaxf(fmaxf(fmaxf(v0[0], v0[1]), fmaxf(v0[2], v0[3])),
                      fmaxf(fmaxf(v1[0], v1[1]), fmaxf(v1[2], v1[3])));
      m = fmaxf(m, __shfl_xor(m, 16));
      m = fmaxf(m, __shfl_xor(m, 32));
      float e0[4], e1[4]; float s = 0.f;
      #pragma unroll
      for (int r = 0; r < 4; ++r){
        e0[r] = __expf(v0[r] - m);
        e1[r] = (g*4 + r < 9) ? __expf(v1[r] - m) : 0.f;
        s += e0[r] + e1[r];
      }
      s += __shfl_xor(s, 16);
      s += __shfl_xor(s, 32);
      float inv = 1.f / s;
      union { unsigned short us[4]; uint2 v; } gp0, gp1;
      #pragma unroll
      for (int r = 0; r < 4; ++r){ gp0.us[r] = f2b(e0[r]*inv); gp1.us[r] = f2b(e1[r]*inv); }
      char* grow = lds + FGT + (w*16 + l15)*80;
      *(uint2*)(grow + g*8)      = gp0.v;
      *(uint2*)(grow + 32 + g*8) = gp1.v;
      __builtin_amdgcn_s_setprio(0);
      #pragma unroll
      for (int kk = 0; kk < 4; ++kk)
        #pragma unroll
        for (int nt = 0; nt < 2; ++nt){
          ah[0][nt] = __builtin_amdgcn_mfma_f32_16x16x32_bf16(xc[kk][0], g1f[nt][kk], ah[0][nt], 0, 0, 0);
          ah[1][nt] = __builtin_amdgcn_mfma_f32_16x16x32_bf16(xc[kk][1], g1f[nt][kk], ah[1][nt], 0, 0, 0);
        }
    } else {
      #pragma unroll
      for (int kk = 0; kk < 4; ++kk)
        #pragma unroll
        for (int nt = 0; nt < 2; ++nt){
          ah[0][nt] = __builtin_amdgcn_mfma_f32_16x16x32_bf16(xc[kk][0], g1f[nt][kk], ah[0][nt], 0, 0, 0);
          ah[1][nt] = __builtin_amdgcn_mfma_f32_16x16x32_bf16(xc[kk][1], g1f[nt][kk], ah[1][nt], 0, 0, 0);
        }
    }
    __syncthreads();                               // barB: GT + XS(next) published

    // ======== P3: ah += G * Z ========
    {
      short8 ga0 = ldfrag(lds + FGT + l15*80 + g*16);
      short8 ga1 = ldfrag(lds + FGT + (16 + l15)*80 + g*16);
      #pragma unroll
      for (int nt = 0; nt < 2; ++nt){
        short8 zb = ldfrag(lds + FZT + (w*32 + nt*16 + l15)*80 + g*16);
        ah[0][nt] = __builtin_amdgcn_mfma_f32_16x16x32_bf16(ga0, zb, ah[0][nt], 0, 0, 0);
        ah[1][nt] = __builtin_amdgcn_mfma_f32_16x16x32_bf16(ga1, zb, ah[1][nt], 0, 0, 0);
      }
    }

    // ---- epilogue: BN2 partials (rows<25) + per-token extreme ----
    #pragma unroll
    for (int n = 0; n < 2; ++n){
      float e = sg[n] ? -3.0e38f : 3.0e38f;
      #pragma unroll
      for (int mt = 0; mt < 2; ++mt)
        #pragma unroll
        for (int r = 0; r < 4; ++r){
          int row = mt*16 + g*4 + r;
          if (row < 25){
            float v = ah[mt][n][r];
            rs[n] += v; rq[n] += v*v;
            e = sg[n] ? fmaxf(e, v) : fminf(e, v);
          }
        }
      float e2 = __shfl_xor(e, 16);
      e = sg[n] ? fmaxf(e, e2) : fminf(e, e2);
      e2 = __shfl_xor(e, 32);
      e = sg[n] ? fmaxf(e, e2) : fminf(e, e2);
      if (g == 0) ext[(size_t)token*256 + oc_[n]] = e;
    }
  }

  // ---- block partials for BN2 ----
  #pragma unroll
  for (int n = 0; n < 2; ++n){
    float s = rs[n], q = rq[n];
    s += __shfl_xor(s, 16); s += __shfl_xor(s, 32);
    q += __shfl_xor(q, 16); q += __shfl_xor(q, 32);
    if (g == 0){
      partials[(size_t)blockIdx.x*512 + oc_[n]]       = s;
      partials[(size_t)blockIdx.x*512 + 256 + oc_[n]] = q;
    }
  }
}

// ---------------- BN2 finalize ----------------
__global__ void kbn2(const float* __restrict__ partials,
                     const float* __restrict__ gg, const float* __restrict__ gb,
                     float* sb)
{
  __shared__ float red[256];
  __shared__ float red2[256];
  int oc = blockIdx.x, tid = threadIdx.x;
  float s = 0.f, q = 0.f;
  for (int i = tid; i < 2048; i += 256){
    s += partials[(size_t)i*512 + oc];
    q += partials[(size_t)i*512 + 256 + oc];
  }
  red[tid] = s; red2[tid] = q;
  __syncthreads();
  for (int off = 128; off > 0; off >>= 1){
    if (tid < off){ red[tid] += red[tid+off]; red2[tid] += red2[tid+off]; }
    __syncthreads();
  }
  if (tid == 0){
    float m = red[0] * (1.f/409600.f);
    float v = red2[0] * (1.f/409600.f) - m*m;
    float rstd = rsqrtf(v + 1e-5f);
    float sc = gg[oc]*rstd;
    sb[oc*2]   = sc;
    sb[oc*2+1] = gb[oc] - m*sc;
  }
}

// ---------------- pass2 ----------------
__global__ void kpass2(const float* __restrict__ ext, const float* __restrict__ sb,
                       float* __restrict__ out)
{
  __shared__ float st[32][257];
  int b = blockIdx.x >> 4, tc = blockIdx.x & 15;
  int t0 = tc*32, tid = threadIdx.x;
  for (int i = tid; i < 32*256; i += 256){
    int tt = i >> 8, oc = i & 255;
    float v = ext[((size_t)(b*512) + t0 + tt)*256 + oc];
    st[tt][oc] = fmaxf(v*sb[oc*2] + sb[oc*2+1], 0.f);
  }
  __syncthreads();
  for (int i = tid; i < 32*256; i += 256){
    int oc = i >> 5, tt = i & 31;
    out[((size_t)(b*256) + oc)*512 + t0 + tt] = st[tt][oc];
  }
}

extern "C" void kernel_launch(void* const* d_in, const int* in_sizes, int n_in,
                              void* d_out, int out_size, void* d_ws, size_t ws_size,
                              hipStream_t stream)
{
  (void)in_sizes; (void)n_in; (void)out_size; (void)ws_size;
  const float* Angle = (const float*)d_in[0];
  const float* dif   = (const float*)d_in[1];
  const float* spa   = (const float*)d_in[2];
  const float* je_g  = (const float*)d_in[3];
  const float* je_b  = (const float*)d_in[4];
  const float* je_w1 = (const float*)d_in[5];
  const float* je_b1 = (const float*)d_in[6];
  const float* je_w2 = (const float*)d_in[7];
  const float* je_b2 = (const float*)d_in[8];
  const float* df_g  = (const float*)d_in[9];
  const float* df_b  = (const float*)d_in[10];
  const float* df_w1 = (const float*)d_in[11];
  const float* df_b1 = (const float*)d_in[12];
  const float* df_w2 = (const float*)d_in[13];
  const float* df_b2 = (const float*)d_in[14];
  const float* sp_w1 = (const float*)d_in[15];
  const float* sp_b1 = (const float*)d_in[16];
  const float* sp_w2 = (const float*)d_in[17];
  const float* sp_b2 = (const float*)d_in[18];
  const float* g1_w  = (const float*)d_in[19];
  const float* g1_b  = (const float*)d_in[20];
  const float* g2_w  = (const float*)d_in[21];
  const float* g2_b  = (const float*)d_in[22];
  const float* gw    = (const float*)d_in[23];
  const float* gw1   = (const float*)d_in[24];
  const float* gw1_b = (const float*)d_in[25];
  const float* gbn_g = (const float*)d_in[26];
  const float* gbn_b = (const float*)d_in[27];
  (void)g2_b;

  char* ws = (char*)d_ws;
  float* sbA     = (float*)(ws + OFF_SBA);
  float* sbD     = (float*)(ws + OFF_SBD);
  unsigned short* spa16 = (unsigned short*)(ws + OFF_SPA16);
  __hip_bfloat16* W2ab = (__hip_bfloat16*)(ws + OFF_W2AB);
  __hip_bfloat16* W2db = (__hip_bfloat16*)(ws + OFF_W2DB);
  float* bn2sb   = (float*)(ws + OFF_BN2SB);
  __hip_bfloat16* ATb  = (__hip_bfloat16*)(ws + OFF_ATB);
  __hip_bfloat16* VVb  = (__hip_bfloat16*)(ws + OFF_VVB);
  __hip_bfloat16* WGb  = (__hip_bfloat16*)(ws + OFF_WGB);
  __hip_bfloat16* WG1b = (__hip_bfloat16*)(ws + OFF_WG1B);
  float* partials = (float*)(ws + OFF_PART);
  float* ext      = (float*)(ws + OFF_EXT);
  unsigned short* X = (unsigned short*)(ws + OFF_XBUF);

  kpre<<<344, 256, 0, stream>>>(gw, gw1, je_w2, df_w2, g1_w, g2_w, g1_b,
                                sp_w1, sp_b1, sp_w2, sp_b2, spa,
                                Angle, dif, je_g, je_b, df_g, df_b,
                                WGb, WG1b, W2ab, W2db, ATb, VVb,
                                spa16, sbA, sbD);
  kembed2<<<4096, 256, 0, stream>>>(Angle, dif, sbA, sbD,
                                    je_w1, je_b1, (const unsigned short*)W2ab, je_b2,
                                    df_w1, df_b1, (const unsigned short*)W2db, df_b2,
                                    spa16, X);
  kfuse<<<2048, 512, 0, stream>>>(X,
                                  (const unsigned short*)ATb,
                                  (const unsigned short*)VVb,
                                  (const unsigned short*)WGb,
                                  (const unsigned short*)WG1b,
                                  gw1_b, gbn_g, ext, partials);
  kbn2<<<256, 256, 0, stream>>>(partials, gbn_g, gbn_b, bn2sb);
  kpass2<<<512, 256, 0, stream>>>(ext, bn2sb, (float*)d_out);
}